// Round 1
// baseline (4400.048 us; speedup 1.0000x reference)
//
#include <hip/hip_runtime.h>

#define EN 2048
#define NBLK 1024
#define NTHR 256
#define CPB 4
#define NGRP 32
#define GSZ 32

// ws float offsets
#define T_OFF   0                        // 64*2048 floats: t_0 .. t_63
#define H_OFF   (64*EN)                  // 2048: intermediate h of each step
#define RT_OFF  (H_OFF + EN)             // 64*2048: res(T, ur1)
#define HT_OFF  (RT_OFF + 64*EN)         // 128*2048: res(TOPS, act_res)
#define BAR_OFF (HT_OFF + 128*EN)        // barrier counters (uints) after this

// ---------------- hierarchical grid barrier (device-scope) ----------------
__device__ __forceinline__ void grid_barrier(unsigned* bar, unsigned bc, int sgrp) {
    __syncthreads();
    if (threadIdx.x == 0) {
        unsigned* sub_cnt = bar;               // 32 counters, 128B stride
        unsigned* sub_gen = bar + NGRP * 32;   // 32 gens, 128B stride
        unsigned* mcnt    = bar + 2 * NGRP * 32;
        __threadfence();
        unsigned old = __hip_atomic_fetch_add(&sub_cnt[sgrp * 32], 1u,
                                              __ATOMIC_RELAXED, __HIP_MEMORY_SCOPE_AGENT);
        if (old == GSZ - 1u) {
            __hip_atomic_store(&sub_cnt[sgrp * 32], 0u, __ATOMIC_RELAXED, __HIP_MEMORY_SCOPE_AGENT);
            __threadfence();
            unsigned mo = __hip_atomic_fetch_add(mcnt, 1u,
                                                 __ATOMIC_RELAXED, __HIP_MEMORY_SCOPE_AGENT);
            if (mo == NGRP - 1u) {
                __hip_atomic_store(mcnt, 0u, __ATOMIC_RELAXED, __HIP_MEMORY_SCOPE_AGENT);
                __threadfence();
#pragma unroll
                for (int t = 0; t < NGRP; ++t)
                    __hip_atomic_store(&sub_gen[t * 32], bc, __ATOMIC_RELAXED, __HIP_MEMORY_SCOPE_AGENT);
            } else {
                while (__hip_atomic_load(&sub_gen[sgrp * 32], __ATOMIC_RELAXED, __HIP_MEMORY_SCOPE_AGENT) < bc)
                    __builtin_amdgcn_s_sleep(1);
            }
        } else {
            while (__hip_atomic_load(&sub_gen[sgrp * 32], __ATOMIC_RELAXED, __HIP_MEMORY_SCOPE_AGENT) < bc)
                __builtin_amdgcn_s_sleep(1);
        }
        __threadfence();
    }
    __syncthreads();
}

// ---------------- persistent chain kernel ----------------
// 1024 blocks: blocks [0,512) own layer-1 (ul1) column slices, [512,1024) own layer-2 (ul2).
// Each block: 4 columns, weight slice in LDS (32 KB). 127 grid barriers total.
__global__ __launch_bounds__(NTHR, 4) void chain_kernel(
    const float* __restrict__ x0,
    const float* __restrict__ ul1W, const float* __restrict__ ul1b,
    const float* __restrict__ ul2W, const float* __restrict__ ul2b,
    float* __restrict__ ws, unsigned* __restrict__ bar, float* __restrict__ out0)
{
    __shared__ float Wsh[CPB][EN];
    __shared__ float red[NTHR / 64][CPB];
    const int tid  = threadIdx.x;
    const int blk  = blockIdx.x;
    const int half = blk >> 9;              // 0 -> layer1, 1 -> layer2
    const int c0   = (blk & 511) * CPB;
    const int sgrp = blk & (NGRP - 1);

    float* Tbuf = ws + T_OFF;
    float* hbuf = ws + H_OFF;

    const float* Wg = half ? ul2W : ul1W;
    const float* bg = half ? ul2b : ul1b;

    // load this block's 4-column weight slice into LDS (16B per row per thread)
#pragma unroll
    for (int u = 0; u < EN / NTHR; ++u) {
        int i = tid + u * NTHR;
        float4 wv = *reinterpret_cast<const float4*>(Wg + (size_t)i * EN + c0);
        Wsh[0][i] = wv.x; Wsh[1][i] = wv.y; Wsh[2][i] = wv.z; Wsh[3][i] = wv.w;
    }
    const float4 bv = *reinterpret_cast<const float4*>(bg + c0);

    if (half == 0 && tid < CPB) Tbuf[c0 + tid] = x0[c0 + tid];

    unsigned bc = 1;
    grid_barrier(bar, bc++, sgrp);

    const float* xin = Tbuf;
    for (int k = 1; k < 64; ++k) {
        // ---- layer 1: hbuf = res(xin) ----
        if (half == 0) {
            float a0 = 0.f, a1 = 0.f, a2 = 0.f, a3 = 0.f;
#pragma unroll
            for (int u = 0; u < EN / (NTHR * 4); ++u) {
                int i4 = tid + u * NTHR;
                float4 xv = reinterpret_cast<const float4*>(xin)[i4];
                float4 w0 = reinterpret_cast<const float4*>(&Wsh[0][0])[i4];
                float4 w1 = reinterpret_cast<const float4*>(&Wsh[1][0])[i4];
                float4 w2 = reinterpret_cast<const float4*>(&Wsh[2][0])[i4];
                float4 w3 = reinterpret_cast<const float4*>(&Wsh[3][0])[i4];
                a0 += xv.x * w0.x + xv.y * w0.y + xv.z * w0.z + xv.w * w0.w;
                a1 += xv.x * w1.x + xv.y * w1.y + xv.z * w1.z + xv.w * w1.w;
                a2 += xv.x * w2.x + xv.y * w2.y + xv.z * w2.z + xv.w * w2.w;
                a3 += xv.x * w3.x + xv.y * w3.y + xv.z * w3.z + xv.w * w3.w;
            }
#pragma unroll
            for (int off = 32; off; off >>= 1) {
                a0 += __shfl_down(a0, off, 64);
                a1 += __shfl_down(a1, off, 64);
                a2 += __shfl_down(a2, off, 64);
                a3 += __shfl_down(a3, off, 64);
            }
            if ((tid & 63) == 0) { int w = tid >> 6; red[w][0] = a0; red[w][1] = a1; red[w][2] = a2; red[w][3] = a3; }
            __syncthreads();
            if (tid == 0) {
                float s0 = red[0][0] + red[1][0] + red[2][0] + red[3][0] + bv.x;
                float s1 = red[0][1] + red[1][1] + red[2][1] + red[3][1] + bv.y;
                float s2 = red[0][2] + red[1][2] + red[2][2] + red[3][2] + bv.z;
                float s3 = red[0][3] + red[1][3] + red[2][3] + red[3][3] + bv.w;
                float4 rv = *reinterpret_cast<const float4*>(xin + c0);
                float4 o;
                o.x = rv.x + fmaxf(s0, 0.f);
                o.y = rv.y + fmaxf(s1, 0.f);
                o.z = rv.z + fmaxf(s2, 0.f);
                o.w = rv.w + fmaxf(s3, 0.f);
                *reinterpret_cast<float4*>(hbuf + c0) = o;
            }
        }
        grid_barrier(bar, bc++, sgrp);

        // ---- layer 2: t_k = res(hbuf) ----
        float* tk = Tbuf + (size_t)k * EN;
        if (half == 1) {
            float a0 = 0.f, a1 = 0.f, a2 = 0.f, a3 = 0.f;
#pragma unroll
            for (int u = 0; u < EN / (NTHR * 4); ++u) {
                int i4 = tid + u * NTHR;
                float4 xv = reinterpret_cast<const float4*>(hbuf)[i4];
                float4 w0 = reinterpret_cast<const float4*>(&Wsh[0][0])[i4];
                float4 w1 = reinterpret_cast<const float4*>(&Wsh[1][0])[i4];
                float4 w2 = reinterpret_cast<const float4*>(&Wsh[2][0])[i4];
                float4 w3 = reinterpret_cast<const float4*>(&Wsh[3][0])[i4];
                a0 += xv.x * w0.x + xv.y * w0.y + xv.z * w0.z + xv.w * w0.w;
                a1 += xv.x * w1.x + xv.y * w1.y + xv.z * w1.z + xv.w * w1.w;
                a2 += xv.x * w2.x + xv.y * w2.y + xv.z * w2.z + xv.w * w2.w;
                a3 += xv.x * w3.x + xv.y * w3.y + xv.z * w3.z + xv.w * w3.w;
            }
#pragma unroll
            for (int off = 32; off; off >>= 1) {
                a0 += __shfl_down(a0, off, 64);
                a1 += __shfl_down(a1, off, 64);
                a2 += __shfl_down(a2, off, 64);
                a3 += __shfl_down(a3, off, 64);
            }
            if ((tid & 63) == 0) { int w = tid >> 6; red[w][0] = a0; red[w][1] = a1; red[w][2] = a2; red[w][3] = a3; }
            __syncthreads();
            if (tid == 0) {
                float s0 = red[0][0] + red[1][0] + red[2][0] + red[3][0] + bv.x;
                float s1 = red[0][1] + red[1][1] + red[2][1] + red[3][1] + bv.y;
                float s2 = red[0][2] + red[1][2] + red[2][2] + red[3][2] + bv.z;
                float s3 = red[0][3] + red[1][3] + red[2][3] + red[3][3] + bv.w;
                float4 rv = *reinterpret_cast<const float4*>(hbuf + c0);
                float4 o;
                o.x = rv.x + fmaxf(s0, 0.f);
                o.y = rv.y + fmaxf(s1, 0.f);
                o.z = rv.z + fmaxf(s2, 0.f);
                o.w = rv.w + fmaxf(s3, 0.f);
                *reinterpret_cast<float4*>(tk + c0) = o;
            }
        }
        grid_barrier(bar, bc++, sgrp);
        xin = tk;
    }

    // out row 0 = t_63
    if (half == 0 && tid < CPB) out0[c0 + tid] = (Tbuf + (size_t)63 * EN)[c0 + tid];
}

// ---------------- batched res-GEMM: C = A + relu(A @ W + b) ----------------
// IN_GATHER: row m < 63 from A0, else from A1 (row m-63). OUT_REV: store row m -> 63-m.
template<int IN_GATHER, int OUT_REV>
__global__ __launch_bounds__(256) void resgemm_kernel(
    const float* __restrict__ A0, const float* __restrict__ A1,
    const float* __restrict__ W, const float* __restrict__ bias,
    float* __restrict__ Cout, int M)
{
    __shared__ float As[16][33];
    __shared__ float Wt[32][64];
    const int tid = threadIdx.x;
    const int c0  = blockIdx.x * 64;
    const int r0  = blockIdx.y * 16;
    const int r   = tid >> 4;
    const int jq  = tid & 15;
    float4 acc = make_float4(0.f, 0.f, 0.f, 0.f);

    int mload = r0 + r; if (mload > M - 1) mload = M - 1;
    const float* arow;
    if (IN_GATHER)
        arow = (mload < 63) ? (A0 + (size_t)mload * EN) : (A1 + (size_t)(mload - 63) * EN);
    else
        arow = A0 + (size_t)mload * EN;

    for (int kt = 0; kt < EN / 32; ++kt) {
        float2 av = *reinterpret_cast<const float2*>(arow + kt * 32 + jq * 2);
        As[r][jq * 2]     = av.x;
        As[r][jq * 2 + 1] = av.y;
#pragma unroll
        for (int u = 0; u < 2; ++u) {
            int idx = tid + 256 * u;
            int kk = idx >> 4, q = idx & 15;
            *reinterpret_cast<float4*>(&Wt[kk][q * 4]) =
                *reinterpret_cast<const float4*>(W + (size_t)(kt * 32 + kk) * EN + c0 + q * 4);
        }
        __syncthreads();
#pragma unroll
        for (int kk = 0; kk < 32; ++kk) {
            float a = As[r][kk];
            float4 wv = *reinterpret_cast<float4*>(&Wt[kk][jq * 4]);
            acc.x += a * wv.x; acc.y += a * wv.y; acc.z += a * wv.z; acc.w += a * wv.w;
        }
        __syncthreads();
    }
    int m = r0 + r;
    if (m < M) {
        int c = c0 + jq * 4;
        float4 rv  = *reinterpret_cast<const float4*>(arow + c);
        float4 bvv = *reinterpret_cast<const float4*>(bias + c);
        float4 o;
        o.x = rv.x + fmaxf(acc.x + bvv.x, 0.f);
        o.y = rv.y + fmaxf(acc.y + bvv.y, 0.f);
        o.z = rv.z + fmaxf(acc.z + bvv.z, 0.f);
        o.w = rv.w + fmaxf(acc.w + bvv.w, 0.f);
        float* op = OUT_REV ? (Cout + (size_t)(63 - m) * EN) : (Cout + (size_t)m * EN);
        *reinterpret_cast<float4*>(op + c) = o;
    }
}

// ---------------- logits: out[131072 + m*2 + c] = HT[m] . actW[:,c] + actb[c] ----------------
__global__ __launch_bounds__(256) void logits_kernel(
    const float* __restrict__ HT, const float* __restrict__ actW,
    const float* __restrict__ actb, float* __restrict__ out)
{
    __shared__ float red[4][2];
    const int m = blockIdx.x, tid = threadIdx.x;
    const float* h = HT + (size_t)m * EN;
    float a0 = 0.f, a1 = 0.f;
#pragma unroll
    for (int u = 0; u < EN / 256; ++u) {
        int i = tid + u * 256;
        float  hv = h[i];
        float2 wv = reinterpret_cast<const float2*>(actW)[i];
        a0 += hv * wv.x;
        a1 += hv * wv.y;
    }
#pragma unroll
    for (int off = 32; off; off >>= 1) { a0 += __shfl_down(a0, off, 64); a1 += __shfl_down(a1, off, 64); }
    if ((tid & 63) == 0) { red[tid >> 6][0] = a0; red[tid >> 6][1] = a1; }
    __syncthreads();
    if (tid == 0) {
        out[64 * EN + m * 2]     = red[0][0] + red[1][0] + red[2][0] + red[3][0] + actb[0];
        out[64 * EN + m * 2 + 1] = red[0][1] + red[1][1] + red[2][1] + red[3][1] + actb[1];
    }
}

extern "C" void kernel_launch(void* const* d_in, const int* in_sizes, int n_in,
                              void* d_out, int out_size, void* d_ws, size_t ws_size,
                              hipStream_t stream)
{
    const float* x0        = (const float*)d_in[0];
    // d_in[1] = fixed_actions (constant 63 reduces + 64 shifts) — structure hardcoded
    const float* act_res_W = (const float*)d_in[2];
    const float* act_res_b = (const float*)d_in[3];
    const float* act_W     = (const float*)d_in[4];
    const float* act_b     = (const float*)d_in[5];
    const float* ul1W      = (const float*)d_in[6];
    const float* ul1b      = (const float*)d_in[7];
    const float* ul2W      = (const float*)d_in[8];
    const float* ul2b      = (const float*)d_in[9];
    const float* ur1W      = (const float*)d_in[10];
    const float* ur1b      = (const float*)d_in[11];
    const float* ur2W      = (const float*)d_in[12];
    const float* ur2b      = (const float*)d_in[13];

    float* ws  = (float*)d_ws;
    float* out = (float*)d_out;
    unsigned* bar = (unsigned*)(ws + BAR_OFF);

    hipMemsetAsync(bar, 0, (2 * NGRP * 32 + 32) * sizeof(unsigned), stream);

    {
        void* args[] = { (void*)&x0, (void*)&ul1W, (void*)&ul1b, (void*)&ul2W, (void*)&ul2b,
                         (void*)&ws, (void*)&bar, (void*)&out };
        hipError_t err = hipLaunchCooperativeKernel(reinterpret_cast<void*>(chain_kernel),
                                                    dim3(NBLK), dim3(NTHR), args, 0, stream);
        if (err != hipSuccess) {
            (void)hipGetLastError();
            // exact-fit grid (4 blocks/CU x 256 CUs) — co-resident in practice
            chain_kernel<<<dim3(NBLK), dim3(NTHR), 0, stream>>>(x0, ul1W, ul1b, ul2W, ul2b, ws, bar, out);
        }
    }

    float* Tbuf = ws + T_OFF;
    float* RT1  = ws + RT_OFF;
    float* HT   = ws + HT_OFF;

    // r-branch: RT1 = res(T[0:63], ur1); out rows 1..63 = res(RT1, ur2) reversed
    resgemm_kernel<0, 0><<<dim3(EN / 64, 4), 256, 0, stream>>>(Tbuf, nullptr, ur1W, ur1b, RT1, 63);
    resgemm_kernel<0, 1><<<dim3(EN / 64, 4), 256, 0, stream>>>(RT1, nullptr, ur2W, ur2b, out, 63);
    // logits hidden: HT = res(TOPS, act_res); TOPS rows 0..62 = T, rows 63..126 = out rows 0..63
    resgemm_kernel<1, 0><<<dim3(EN / 64, 8), 256, 0, stream>>>(Tbuf, out, act_res_W, act_res_b, HT, 127);
    logits_kernel<<<dim3(127), 256, 0, stream>>>(HT, act_W, act_b, out);
}

// Round 2
// 703.956 us; speedup vs baseline: 6.2505x; 6.2505x over previous
//
#include <hip/hip_runtime.h>

#define EN 2048
#define NCH 256        // chain blocks (1 per CU)
#define CTH 1024       // chain threads per block
#define COLS 16        // output columns per chain block
#define NSPLIT 2
#define KSPL (EN / NSPLIT)

// ws float offsets
#define T_OFF    0                 // 64*2048: t_0..t_63
#define H_OFF    (64 * EN)         // 64*2048: h slots (k=1..63); reused as RT1 after chain
#define HT_OFF   (128 * EN)        // 127*2048 (padded to 64 rows *2)
#define P_OFF    (192 * EN)        // 2*128*2048 partials
#define FLAG_OFF (P_OFF + 256 * EN) // 256 uints after this (float offset)

// ---------------- fence-free flag poll (wave 0 only, 128 flags) ----------------
__device__ __forceinline__ void poll128(const unsigned* f, unsigned k, int lane) {
    for (;;) {
        unsigned a = __hip_atomic_load(&f[lane],      __ATOMIC_RELAXED, __HIP_MEMORY_SCOPE_AGENT);
        unsigned b = __hip_atomic_load(&f[64 + lane], __ATOMIC_RELAXED, __HIP_MEMORY_SCOPE_AGENT);
        int ok = __all((int)(a >= k)) & __all((int)(b >= k));
        if (ok) break;
        __builtin_amdgcn_s_sleep(1);
    }
    asm volatile("" ::: "memory");
}

// ---------------- persistent chain kernel ----------------
// blocks [0,128): layer-1 (ul1) 16-col slices; [128,256): layer-2 (ul2).
// Weights live in VGPRs (32 floats/thread). No fences anywhere: sc1 atomics only.
__global__ __launch_bounds__(CTH, 1) void chain_kernel(
    const float* __restrict__ x0,
    const float* __restrict__ ul1W, const float* __restrict__ ul1b,
    const float* __restrict__ ul2W, const float* __restrict__ ul2b,
    float* __restrict__ T, float* __restrict__ H,
    float* __restrict__ out0, unsigned* __restrict__ flags)
{
    __shared__ __align__(16) float xs[EN];
    __shared__ float red[16][16];
    __shared__ float bias_s[COLS];

    const int tid   = threadIdx.x;
    const int half  = blockIdx.x >> 7;       // 0 -> layer1, 1 -> layer2
    const int idx   = blockIdx.x & 127;
    const int c0    = idx * COLS;
    const int col   = tid & 15;
    const int chunk = tid >> 4;               // 0..63
    const int lane  = tid & 63;
    const int wv    = tid >> 6;               // wave id 0..15

    const float* Wg = half ? ul2W : ul1W;
    const float* bg = half ? ul2b : ul1b;
    unsigned* myflag    = half ? &flags[128 + idx] : &flags[idx];
    const unsigned* inf = half ? &flags[0] : &flags[128];

    // preload 32 weight values per thread: rows chunk*32..+31 of column c0+col
    float4 w[8];
#pragma unroll
    for (int j = 0; j < 8; ++j) {
        const float* wp = Wg + (size_t)(chunk * 32 + j * 4) * EN + c0 + col;
        w[j].x = wp[0]; w[j].y = wp[EN]; w[j].z = wp[2 * EN]; w[j].w = wp[3 * EN];
    }
    if (tid < COLS) bias_s[tid] = bg[c0 + tid];

    for (int k = 1; k <= 63; ++k) {
        if (wv == 0) {
            if (half) poll128(inf, (unsigned)k, lane);
            else if (k >= 2) poll128(inf, (unsigned)(k - 1), lane);
        }
        __syncthreads();
        const float* src = half ? (H + (size_t)k * EN)
                                : (k == 1 ? x0 : T + (size_t)(k - 1) * EN);
        reinterpret_cast<float2*>(xs)[tid] = reinterpret_cast<const float2*>(src)[tid];
        __syncthreads();

        // dot: 16-lane broadcast groups read the same 16B from LDS
        float s = 0.f;
        const float4* xv = reinterpret_cast<const float4*>(xs) + chunk * 8;
#pragma unroll
        for (int j = 0; j < 8; ++j) {
            float4 x4 = xv[j];
            s += x4.x * w[j].x + x4.y * w[j].y + x4.z * w[j].z + x4.w * w[j].w;
        }
        s += __shfl_xor(s, 16, 64);
        s += __shfl_xor(s, 32, 64);
        if (lane < 16) red[wv][lane] = s;
        __syncthreads();

        if (wv == 0) {
            if (lane < 16) {
                float tot = bias_s[lane];
#pragma unroll
                for (int q = 0; q < 16; ++q) tot += red[q][lane];
                float o = xs[c0 + lane] + fmaxf(tot, 0.f);
                float* dst = half ? (T + (size_t)k * EN) : (H + (size_t)k * EN);
                __hip_atomic_store(&dst[c0 + lane], o, __ATOMIC_RELAXED, __HIP_MEMORY_SCOPE_AGENT);
                if (half && k == 63) out0[c0 + lane] = o;          // out row 0 = t_63
                if (!half && k == 1) T[c0 + lane] = xs[c0 + lane]; // T row 0 = x0
            }
            asm volatile("s_waitcnt vmcnt(0)" ::: "memory");
            if (lane == 0)
                __hip_atomic_store(myflag, (unsigned)k, __ATOMIC_RELAXED, __HIP_MEMORY_SCOPE_AGENT);
        }
    }
}

// ---------------- K-split partial GEMM: P[ks] = A[:, ks-range] @ W[ks-range, :] ----------------
// 64-row x 64-col tile per block, K=1024 per split, register-prefetch pipelined.
template<int GATHER>
__global__ __launch_bounds__(256) void gemm_part(
    const float* __restrict__ A0, const float* __restrict__ A1,
    const float* __restrict__ W, float* __restrict__ P, int M)
{
    __shared__ float As[32][68];   // [k][row], 68*4B = 272B row stride (16B-aligned, bank-spread)
    __shared__ float Ws[32][68];   // [k][col]
    const int tid = threadIdx.x;
    const int c0  = blockIdx.x * 64;
    const int ks  = blockIdx.y;
    const int my  = blockIdx.z * 64;
    const int tr  = tid >> 4, tc = tid & 15;

    float4 acc[4];
#pragma unroll
    for (int i = 0; i < 4; ++i) acc[i] = make_float4(0.f, 0.f, 0.f, 0.f);

    const int am = tid >> 2, akq = tid & 3;
    int mg = my + am; if (mg > M - 1) mg = M - 1;
    const float* arow;
    if (GATHER) arow = (mg < 63) ? (A0 + (size_t)mg * EN) : (A1 + (size_t)(mg - 63) * EN);
    else        arow = A0 + (size_t)mg * EN;
    const int wk = tid >> 3, wq = tid & 7;
    const int k0base = ks * KSPL;

    float4 ra0, ra1, rw0, rw1;
    {
        ra0 = *reinterpret_cast<const float4*>(arow + k0base + akq * 8);
        ra1 = *reinterpret_cast<const float4*>(arow + k0base + akq * 8 + 4);
        const float* wp = W + (size_t)(k0base + wk) * EN + c0 + wq * 8;
        rw0 = *reinterpret_cast<const float4*>(wp);
        rw1 = *reinterpret_cast<const float4*>(wp + 4);
    }
    for (int kt = 0; kt < KSPL / 32; ++kt) {
        __syncthreads();
        As[akq * 8 + 0][am] = ra0.x; As[akq * 8 + 1][am] = ra0.y;
        As[akq * 8 + 2][am] = ra0.z; As[akq * 8 + 3][am] = ra0.w;
        As[akq * 8 + 4][am] = ra1.x; As[akq * 8 + 5][am] = ra1.y;
        As[akq * 8 + 6][am] = ra1.z; As[akq * 8 + 7][am] = ra1.w;
        *reinterpret_cast<float4*>(&Ws[wk][wq * 8])     = rw0;
        *reinterpret_cast<float4*>(&Ws[wk][wq * 8 + 4]) = rw1;
        __syncthreads();
        if (kt + 1 < KSPL / 32) {
            int k0 = k0base + (kt + 1) * 32;
            ra0 = *reinterpret_cast<const float4*>(arow + k0 + akq * 8);
            ra1 = *reinterpret_cast<const float4*>(arow + k0 + akq * 8 + 4);
            const float* wp = W + (size_t)(k0 + wk) * EN + c0 + wq * 8;
            rw0 = *reinterpret_cast<const float4*>(wp);
            rw1 = *reinterpret_cast<const float4*>(wp + 4);
        }
#pragma unroll
        for (int kk = 0; kk < 32; ++kk) {
            float4 av  = *reinterpret_cast<const float4*>(&As[kk][tr * 4]);
            float4 wv4 = *reinterpret_cast<const float4*>(&Ws[kk][tc * 4]);
            acc[0].x += av.x * wv4.x; acc[0].y += av.x * wv4.y; acc[0].z += av.x * wv4.z; acc[0].w += av.x * wv4.w;
            acc[1].x += av.y * wv4.x; acc[1].y += av.y * wv4.y; acc[1].z += av.y * wv4.z; acc[1].w += av.y * wv4.w;
            acc[2].x += av.z * wv4.x; acc[2].y += av.z * wv4.y; acc[2].z += av.z * wv4.z; acc[2].w += av.z * wv4.w;
            acc[3].x += av.w * wv4.x; acc[3].y += av.w * wv4.y; acc[3].z += av.w * wv4.z; acc[3].w += av.w * wv4.w;
        }
    }
#pragma unroll
    for (int i = 0; i < 4; ++i) {
        int m = my + tr * 4 + i;
        *reinterpret_cast<float4*>(&P[((size_t)ks * 128 + m) * EN + c0 + tc * 4]) = acc[i];
    }
}

// ---------------- epilogue: C = gatherA + relu(P0 + P1 + bias), optional row reverse ----------------
template<int GATHER, int REV>
__global__ __launch_bounds__(256) void epilogue_kernel(
    const float* __restrict__ A0, const float* __restrict__ A1,
    const float* __restrict__ P, const float* __restrict__ bias,
    float* __restrict__ C)
{
    const int m = blockIdx.y;
    const int c = blockIdx.x * 256 + threadIdx.x;
    const float* arow;
    if (GATHER) arow = (m < 63) ? (A0 + (size_t)m * EN) : (A1 + (size_t)(m - 63) * EN);
    else        arow = A0 + (size_t)m * EN;
    float p = P[(size_t)m * EN + c] + P[(size_t)(128 + m) * EN + c];
    float o = arow[c] + fmaxf(p + bias[c], 0.f);
    float* crow = REV ? (C + (size_t)(63 - m) * EN) : (C + (size_t)m * EN);
    crow[c] = o;
}

// ---------------- logits ----------------
__global__ __launch_bounds__(256) void logits_kernel(
    const float* __restrict__ HT, const float* __restrict__ actW,
    const float* __restrict__ actb, float* __restrict__ out)
{
    __shared__ float red[4][2];
    const int m = blockIdx.x, tid = threadIdx.x;
    const float* h = HT + (size_t)m * EN;
    float a0 = 0.f, a1 = 0.f;
#pragma unroll
    for (int u = 0; u < EN / 256; ++u) {
        int i = tid + u * 256;
        float  hv = h[i];
        float2 wvv = reinterpret_cast<const float2*>(actW)[i];
        a0 += hv * wvv.x;
        a1 += hv * wvv.y;
    }
#pragma unroll
    for (int off = 32; off; off >>= 1) { a0 += __shfl_down(a0, off, 64); a1 += __shfl_down(a1, off, 64); }
    if ((tid & 63) == 0) { red[tid >> 6][0] = a0; red[tid >> 6][1] = a1; }
    __syncthreads();
    if (tid == 0) {
        out[64 * EN + m * 2]     = red[0][0] + red[1][0] + red[2][0] + red[3][0] + actb[0];
        out[64 * EN + m * 2 + 1] = red[0][1] + red[1][1] + red[2][1] + red[3][1] + actb[1];
    }
}

extern "C" void kernel_launch(void* const* d_in, const int* in_sizes, int n_in,
                              void* d_out, int out_size, void* d_ws, size_t ws_size,
                              hipStream_t stream)
{
    const float* x0        = (const float*)d_in[0];
    // d_in[1] = fixed_actions (constant 63 reduces + 64 shifts) — structure hardcoded
    const float* act_res_W = (const float*)d_in[2];
    const float* act_res_b = (const float*)d_in[3];
    const float* act_W     = (const float*)d_in[4];
    const float* act_b     = (const float*)d_in[5];
    const float* ul1W      = (const float*)d_in[6];
    const float* ul1b      = (const float*)d_in[7];
    const float* ul2W      = (const float*)d_in[8];
    const float* ul2b      = (const float*)d_in[9];
    const float* ur1W      = (const float*)d_in[10];
    const float* ur1b      = (const float*)d_in[11];
    const float* ur2W      = (const float*)d_in[12];
    const float* ur2b      = (const float*)d_in[13];

    float* ws  = (float*)d_ws;
    float* out = (float*)d_out;
    float* T   = ws + T_OFF;
    float* H   = ws + H_OFF;    // chain h slots; reused as RT1 after chain
    float* RT1 = ws + H_OFF;
    float* HT  = ws + HT_OFF;
    float* P   = ws + P_OFF;
    unsigned* flags = (unsigned*)(ws + FLAG_OFF);

    hipMemsetAsync(flags, 0, 256 * sizeof(unsigned), stream);

    {
        void* args[] = { (void*)&x0, (void*)&ul1W, (void*)&ul1b, (void*)&ul2W, (void*)&ul2b,
                         (void*)&T, (void*)&H, (void*)&out, (void*)&flags };
        hipError_t err = hipLaunchCooperativeKernel(reinterpret_cast<void*>(chain_kernel),
                                                    dim3(NCH), dim3(CTH), args, 0, stream);
        if (err != hipSuccess) {
            (void)hipGetLastError();
            // 256 blocks x 1024 threads = exactly 1 block/CU -> co-resident
            chain_kernel<<<dim3(NCH), dim3(CTH), 0, stream>>>(x0, ul1W, ul1b, ul2W, ul2b, T, H, out, flags);
        }
    }

    // stage A: RT1 = res(T[0:63], ur1)
    gemm_part<0><<<dim3(32, NSPLIT, 1), 256, 0, stream>>>(T, nullptr, ur1W, P, 63);
    epilogue_kernel<0, 0><<<dim3(8, 63), 256, 0, stream>>>(T, nullptr, P, ur1b, RT1);
    // stage B: out rows 1..63 = res(RT1, ur2), reversed
    gemm_part<0><<<dim3(32, NSPLIT, 1), 256, 0, stream>>>(RT1, nullptr, ur2W, P, 63);
    epilogue_kernel<0, 1><<<dim3(8, 63), 256, 0, stream>>>(RT1, nullptr, P, ur2b, out);
    // stage C: HT = res(TOPS, act_res); TOPS rows 0..62 = T, rows 63..126 = out rows 0..63
    gemm_part<1><<<dim3(32, NSPLIT, 2), 256, 0, stream>>>(T, out, act_res_W, P, 127);
    epilogue_kernel<1, 0><<<dim3(8, 127), 256, 0, stream>>>(T, out, P, act_res_b, HT);
    // logits
    logits_kernel<<<dim3(127), 256, 0, stream>>>(HT, act_W, act_b, out);
}

// Round 3
// 328.502 us; speedup vs baseline: 13.3943x; 2.1429x over previous
//
#include <hip/hip_runtime.h>

#define EN 2048
#define NCH 256        // chain blocks (1 per CU)
#define CTH 1024       // chain threads per block
#define COLS 16        // output columns per chain block

// ws float offsets
#define T_OFF    0                 // 64*2048: t_0..t_63   (rows 1..63 sentinel-polled)
#define H_OFF    (64 * EN)         // 64*2048: h slots     (rows 1..63 sentinel-polled); reused as RT1
#define HT_OFF   (128 * EN)        // 127*2048: res(TOPS, act_res)
#define P_OFF    (256 * EN)        // 8*64*2048 partials (4 MB)

#define SENT 0xFFFFFFFFu

// ---------------- persistent chain kernel (pure dataflow, sentinel-poll) ----------------
// blocks [0,128): layer-1 (ul1) 16-col slices; [128,256): layer-2 (ul2).
// Weights live in VGPRs (32 floats/thread). No flags, no fences, no acks:
// producers store sc1 data; consumers poll the data bytes they consume.
__global__ __launch_bounds__(CTH, 1) void chain_kernel(
    const float* __restrict__ x0,
    const float* __restrict__ ul1W, const float* __restrict__ ul1b,
    const float* __restrict__ ul2W, const float* __restrict__ ul2b,
    float* __restrict__ T, float* __restrict__ H, float* __restrict__ out0)
{
    __shared__ __align__(16) float xs[EN];
    __shared__ float red[16][17];
    __shared__ float bias_s[COLS];

    const int tid   = threadIdx.x;
    const int half  = blockIdx.x >> 7;       // 0 -> layer1, 1 -> layer2
    const int idx   = blockIdx.x & 127;
    const int c0    = idx * COLS;
    const int col   = tid & 15;
    const int chunk = tid >> 4;               // 0..63
    const int lane  = tid & 63;
    const int wv    = tid >> 6;               // wave id 0..15

    const float* Wg = half ? ul2W : ul1W;
    const float* bg = half ? ul2b : ul1b;

    // preload 32 weight values per thread: rows chunk*32..+31 of column c0+col
    float4 w[8];
#pragma unroll
    for (int j = 0; j < 8; ++j) {
        const float* wp = Wg + (size_t)(chunk * 32 + j * 4) * EN + c0 + col;
        w[j].x = wp[0]; w[j].y = wp[EN]; w[j].z = wp[2 * EN]; w[j].w = wp[3 * EN];
    }
    if (tid < COLS) bias_s[tid] = bg[c0 + tid];

    for (int k = 1; k <= 63; ++k) {
        // ---- acquire x into xs ----
        if (half == 0 && k == 1) {
            reinterpret_cast<float2*>(xs)[tid] = reinterpret_cast<const float2*>(x0)[tid];
        } else {
            const float* src = half ? (H + (size_t)k * EN) : (T + (size_t)(k - 1) * EN);
            const unsigned long long* s64 =
                reinterpret_cast<const unsigned long long*>(src) + (size_t)wv * 64 + lane;
            unsigned long long v;
            for (;;) {
                v = __hip_atomic_load(s64, __ATOMIC_RELAXED, __HIP_MEMORY_SCOPE_AGENT);
                unsigned lo = (unsigned)v, hi = (unsigned)(v >> 32);
                if (!__any((int)(lo == SENT || hi == SENT))) break;
            }
            float2 xv;
            xv.x = __uint_as_float((unsigned)v);
            xv.y = __uint_as_float((unsigned)(v >> 32));
            reinterpret_cast<float2*>(xs)[tid] = xv;   // tid == wv*64+lane
        }
        __syncthreads();

        // ---- dot: 16-lane broadcast groups read the same 16B from LDS ----
        float s = 0.f;
        const float4* xv4 = reinterpret_cast<const float4*>(xs) + chunk * 8;
#pragma unroll
        for (int j = 0; j < 8; ++j) {
            float4 x4 = xv4[j];
            s += x4.x * w[j].x + x4.y * w[j].y + x4.z * w[j].z + x4.w * w[j].w;
        }
        s += __shfl_xor(s, 16, 64);
        s += __shfl_xor(s, 32, 64);
        if (lane < 16) red[wv][lane] = s;
        __syncthreads();

        // ---- tail: wave 0 reduces 16 waves, stores 16 outputs (no ack, no flag) ----
        if (wv == 0 && lane < 16) {
            float tot = bias_s[lane];
#pragma unroll
            for (int q = 0; q < 16; ++q) tot += red[q][lane];
            float o = xs[c0 + lane] + fmaxf(tot, 0.f);
            float* dst = half ? (T + (size_t)k * EN) : (H + (size_t)k * EN);
            __hip_atomic_store((unsigned*)&dst[c0 + lane], __float_as_uint(o),
                               __ATOMIC_RELAXED, __HIP_MEMORY_SCOPE_AGENT);
            if (half && k == 63) out0[c0 + lane] = o;          // out row 0 = t_63
            if (!half && k == 1) T[c0 + lane] = xs[c0 + lane]; // T row 0 = x0
        }
        // No barrier needed: other waves overwrite xs only after their next poll
        // succeeds, which transitively requires this block's stores to be consumed.
    }
}

// ---------------- K-split partial GEMM: P[ks] = A[:, ks-range] @ W[ks-range, :] ----------------
// 64-row x 64-col tile per block, register-prefetch pipelined.
template<int GATHER, int NS, int MR>
__global__ __launch_bounds__(256) void gemm_part(
    const float* __restrict__ A0, const float* __restrict__ A1,
    const float* __restrict__ W, float* __restrict__ P, int M)
{
    __shared__ float As[32][68];
    __shared__ float Ws[32][68];
    const int KSPL = EN / NS;
    const int tid = threadIdx.x;
    const int c0  = blockIdx.x * 64;
    const int ks  = blockIdx.y;
    const int my  = blockIdx.z * 64;
    const int tr  = tid >> 4, tc = tid & 15;

    float4 acc[4];
#pragma unroll
    for (int i = 0; i < 4; ++i) acc[i] = make_float4(0.f, 0.f, 0.f, 0.f);

    const int am = tid >> 2, akq = tid & 3;
    int mg = my + am; if (mg > M - 1) mg = M - 1;
    const float* arow;
    if (GATHER) arow = (mg < 63) ? (A0 + (size_t)mg * EN) : (A1 + (size_t)(mg - 63) * EN);
    else        arow = A0 + (size_t)mg * EN;
    const int wk = tid >> 3, wq = tid & 7;
    const int k0base = ks * KSPL;

    float4 ra0, ra1, rw0, rw1;
    {
        ra0 = *reinterpret_cast<const float4*>(arow + k0base + akq * 8);
        ra1 = *reinterpret_cast<const float4*>(arow + k0base + akq * 8 + 4);
        const float* wp = W + (size_t)(k0base + wk) * EN + c0 + wq * 8;
        rw0 = *reinterpret_cast<const float4*>(wp);
        rw1 = *reinterpret_cast<const float4*>(wp + 4);
    }
    for (int kt = 0; kt < KSPL / 32; ++kt) {
        __syncthreads();
        As[akq * 8 + 0][am] = ra0.x; As[akq * 8 + 1][am] = ra0.y;
        As[akq * 8 + 2][am] = ra0.z; As[akq * 8 + 3][am] = ra0.w;
        As[akq * 8 + 4][am] = ra1.x; As[akq * 8 + 5][am] = ra1.y;
        As[akq * 8 + 6][am] = ra1.z; As[akq * 8 + 7][am] = ra1.w;
        *reinterpret_cast<float4*>(&Ws[wk][wq * 8])     = rw0;
        *reinterpret_cast<float4*>(&Ws[wk][wq * 8 + 4]) = rw1;
        __syncthreads();
        if (kt + 1 < KSPL / 32) {
            int k0 = k0base + (kt + 1) * 32;
            ra0 = *reinterpret_cast<const float4*>(arow + k0 + akq * 8);
            ra1 = *reinterpret_cast<const float4*>(arow + k0 + akq * 8 + 4);
            const float* wp = W + (size_t)(k0 + wk) * EN + c0 + wq * 8;
            rw0 = *reinterpret_cast<const float4*>(wp);
            rw1 = *reinterpret_cast<const float4*>(wp + 4);
        }
#pragma unroll
        for (int kk = 0; kk < 32; ++kk) {
            float4 av  = *reinterpret_cast<const float4*>(&As[kk][tr * 4]);
            float4 wv4 = *reinterpret_cast<const float4*>(&Ws[kk][tc * 4]);
            acc[0].x += av.x * wv4.x; acc[0].y += av.x * wv4.y; acc[0].z += av.x * wv4.z; acc[0].w += av.x * wv4.w;
            acc[1].x += av.y * wv4.x; acc[1].y += av.y * wv4.y; acc[1].z += av.y * wv4.z; acc[1].w += av.y * wv4.w;
            acc[2].x += av.z * wv4.x; acc[2].y += av.z * wv4.y; acc[2].z += av.z * wv4.z; acc[2].w += av.z * wv4.w;
            acc[3].x += av.w * wv4.x; acc[3].y += av.w * wv4.y; acc[3].z += av.w * wv4.z; acc[3].w += av.w * wv4.w;
        }
    }
#pragma unroll
    for (int i = 0; i < 4; ++i) {
        int m = my + tr * 4 + i;
        *reinterpret_cast<float4*>(&P[((size_t)ks * MR + m) * EN + c0 + tc * 4]) = acc[i];
    }
}

// ---------------- epilogue: C = gatherA + relu(sum_ks P[ks] + bias), optional row reverse ----------------
template<int GATHER, int REV, int NS, int MR>
__global__ __launch_bounds__(256) void epilogue_kernel(
    const float* __restrict__ A0, const float* __restrict__ A1,
    const float* __restrict__ P, const float* __restrict__ bias,
    float* __restrict__ C)
{
    const int m = blockIdx.y;
    const int c = blockIdx.x * 256 + threadIdx.x;
    const float* arow;
    if (GATHER) arow = (m < 63) ? (A0 + (size_t)m * EN) : (A1 + (size_t)(m - 63) * EN);
    else        arow = A0 + (size_t)m * EN;
    float p = 0.f;
#pragma unroll
    for (int ks = 0; ks < NS; ++ks)
        p += P[((size_t)ks * MR + m) * EN + c];
    float o = arow[c] + fmaxf(p + bias[c], 0.f);
    float* crow = REV ? (C + (size_t)(63 - m) * EN) : (C + (size_t)m * EN);
    crow[c] = o;
}

// ---------------- logits ----------------
__global__ __launch_bounds__(256) void logits_kernel(
    const float* __restrict__ HT, const float* __restrict__ actW,
    const float* __restrict__ actb, float* __restrict__ out)
{
    __shared__ float red[4][2];
    const int m = blockIdx.x, tid = threadIdx.x;
    const float* h = HT + (size_t)m * EN;
    float a0 = 0.f, a1 = 0.f;
#pragma unroll
    for (int u = 0; u < EN / 256; ++u) {
        int i = tid + u * 256;
        float  hv = h[i];
        float2 wvv = reinterpret_cast<const float2*>(actW)[i];
        a0 += hv * wvv.x;
        a1 += hv * wvv.y;
    }
#pragma unroll
    for (int off = 32; off; off >>= 1) { a0 += __shfl_down(a0, off, 64); a1 += __shfl_down(a1, off, 64); }
    if ((tid & 63) == 0) { red[tid >> 6][0] = a0; red[tid >> 6][1] = a1; }
    __syncthreads();
    if (tid == 0) {
        out[64 * EN + m * 2]     = red[0][0] + red[1][0] + red[2][0] + red[3][0] + actb[0];
        out[64 * EN + m * 2 + 1] = red[0][1] + red[1][1] + red[2][1] + red[3][1] + actb[1];
    }
}

extern "C" void kernel_launch(void* const* d_in, const int* in_sizes, int n_in,
                              void* d_out, int out_size, void* d_ws, size_t ws_size,
                              hipStream_t stream)
{
    const float* x0        = (const float*)d_in[0];
    // d_in[1] = fixed_actions (constant 63 reduces + 64 shifts) — structure hardcoded
    const float* act_res_W = (const float*)d_in[2];
    const float* act_res_b = (const float*)d_in[3];
    const float* act_W     = (const float*)d_in[4];
    const float* act_b     = (const float*)d_in[5];
    const float* ul1W      = (const float*)d_in[6];
    const float* ul1b      = (const float*)d_in[7];
    const float* ul2W      = (const float*)d_in[8];
    const float* ul2b      = (const float*)d_in[9];
    const float* ur1W      = (const float*)d_in[10];
    const float* ur1b      = (const float*)d_in[11];
    const float* ur2W      = (const float*)d_in[12];
    const float* ur2b      = (const float*)d_in[13];

    float* ws  = (float*)d_ws;
    float* out = (float*)d_out;
    float* T   = ws + T_OFF;
    float* H   = ws + H_OFF;    // chain h slots; reused as RT1 after chain
    float* RT1 = ws + H_OFF;
    float* HT  = ws + HT_OFF;
    float* P   = ws + P_OFF;

    // sentinel-fill T+H (1 MB) — poll-on-data readiness protocol
    hipMemsetAsync(ws, 0xFF, (size_t)128 * EN * sizeof(float), stream);

    {
        void* args[] = { (void*)&x0, (void*)&ul1W, (void*)&ul1b, (void*)&ul2W, (void*)&ul2b,
                         (void*)&T, (void*)&H, (void*)&out };
        hipError_t err = hipLaunchCooperativeKernel(reinterpret_cast<void*>(chain_kernel),
                                                    dim3(NCH), dim3(CTH), args, 0, stream);
        if (err != hipSuccess) {
            (void)hipGetLastError();
            // 256 blocks x 1024 threads = exactly 1 block/CU -> co-resident
            chain_kernel<<<dim3(NCH), dim3(CTH), 0, stream>>>(x0, ul1W, ul1b, ul2W, ul2b, T, H, out);
        }
    }

    // stage A: RT1 = res(T[0:63], ur1)
    gemm_part<0, 8, 64><<<dim3(32, 8, 1), 256, 0, stream>>>(T, nullptr, ur1W, P, 63);
    epilogue_kernel<0, 0, 8, 64><<<dim3(8, 63), 256, 0, stream>>>(T, nullptr, P, ur1b, RT1);
    // stage B: out rows 1..63 = res(RT1, ur2), reversed
    gemm_part<0, 8, 64><<<dim3(32, 8, 1), 256, 0, stream>>>(RT1, nullptr, ur2W, P, 63);
    epilogue_kernel<0, 1, 8, 64><<<dim3(8, 63), 256, 0, stream>>>(RT1, nullptr, P, ur2b, out);
    // stage C: HT = res(TOPS, act_res); TOPS rows 0..62 = T, rows 63..126 = out rows 0..63
    gemm_part<1, 4, 128><<<dim3(32, 4, 2), 256, 0, stream>>>(T, out, act_res_W, P, 127);
    epilogue_kernel<1, 0, 4, 128><<<dim3(8, 127), 256, 0, stream>>>(T, out, P, act_res_b, HT);
    // logits
    logits_kernel<<<dim3(127), 256, 0, stream>>>(HT, act_W, act_b, out);
}